// Round 3
// baseline (144.480 us; speedup 1.0000x reference)
//
#include <hip/hip_runtime.h>

// YOLO loss: per-cell masked squared-error reduction over [B,7,7,30] fp32 x2.
// Per cell: mask = (gt[...,4] == 1.0)
//   per_cell = mask ? 5*sum((pre[0:4]-gt[0:4])^2) + 10*(pre[4]-gt[4])^2
//                   : 0.5*(pre[4]-gt[4])^2
// Output: scalar sum, shape (1,).
//
// At 128 B cache-line granularity every line of both inputs contains needed
// channels (needed 20 B regions are 120 B-strided < 128 B), so HBM traffic is
// irreducibly the full 771 MB. Therefore: read EVERYTHING as a perfectly
// contiguous float4 stream (max-BW pattern) and compute per-chunk roles
// arithmetically.
//
// Chunk role r = c % 15 (2-cell period = 60 floats = 15 float4 chunks):
//   r=0: cell0 coords 0-3 (all comps)        mask from next chunk's g.x
//   r=1: cell0 conf in comp x (local mask)
//   r=7: cell1 coords 0,1 in comps z,w       mask from next chunk's g.z
//   r=8: cell1 coords 2,3 in comps x,y + conf in comp z (local mask)
//   else: no contribution.
// Next chunk = next lane (contiguous assignment); lane 63 patches via a
// single predicated scalar load. Final partial-wave boundary lane always has
// role 14 (total % 15 == 0), so it never consumes an undefined shuffle.

__global__ __launch_bounds__(256) void yolo_loss_kernel(
    const float* __restrict__ pre,
    const float* __restrict__ gt,
    float* __restrict__ out,
    unsigned int total_f4)
{
    unsigned int tid    = blockIdx.x * blockDim.x + threadIdx.x;
    unsigned int stride = gridDim.x * blockDim.x;
    const int lane = threadIdx.x & 63;

    float acc = 0.0f;
    for (unsigned int c = tid; c < total_f4; c += stride) {
        const float4 p = *reinterpret_cast<const float4*>(pre + (size_t)c * 4);
        const float4 g = *reinterpret_cast<const float4*>(gt  + (size_t)c * 4);

        unsigned int r = c % 15u;   // compiler: magic-mul, no divide

        // conf channels for coord chunks live one lane up
        float nx = __shfl_down(g.x, 1, 64);
        float nz = __shfl_down(g.z, 1, 64);
        if (lane == 63 && (r == 0u || r == 7u)) {
            const float* gn = gt + (size_t)(c + 1) * 4;  // in-bounds: r<14
            if (r == 0u) nx = gn[0];
            else         nz = gn[2];
        }

        float dx = p.x - g.x, dy = p.y - g.y, dz = p.z - g.z, dw = p.w - g.w;
        float s01 = dx * dx + dy * dy;
        float s23 = dz * dz + dw * dw;

        float contrib = 0.0f;
        if (r == 0u) {
            contrib = (nx == 1.0f) ? 5.0f * (s01 + s23) : 0.0f;
        } else if (r == 1u) {
            float c0 = dx * dx;
            contrib = (g.x == 1.0f) ? 10.0f * c0 : 0.5f * c0;
        } else if (r == 7u) {
            contrib = (nz == 1.0f) ? 5.0f * s23 : 0.0f;
        } else if (r == 8u) {
            float c2 = dz * dz;
            contrib = (g.z == 1.0f) ? fmaf(5.0f, s01, 10.0f * c2) : 0.5f * c2;
        }
        acc += contrib;
    }

    // wave-64 shuffle-down reduction
    for (int offr = 32; offr > 0; offr >>= 1)
        acc += __shfl_down(acc, offr, 64);

    __shared__ float s[4];
    int wid = threadIdx.x >> 6;
    if (lane == 0) s[wid] = acc;
    __syncthreads();

    if (threadIdx.x == 0) {
        float total = s[0] + s[1] + s[2] + s[3];
        atomicAdd(out, total);   // device-scope by default on CDNA
    }
}

extern "C" void kernel_launch(void* const* d_in, const int* in_sizes, int n_in,
                              void* d_out, int out_size, void* d_ws, size_t ws_size,
                              hipStream_t stream) {
    const float* pre = (const float*)d_in[0];
    const float* gt  = (const float*)d_in[1];
    float* out = (float*)d_out;

    // d_out is poisoned once and never re-poisoned between replays: zero it
    // ourselves every call (stream op — graph-capture safe).
    hipMemsetAsync(out, 0, sizeof(float), stream);

    unsigned int total_f4 = (unsigned int)(in_sizes[0] / 4);  // 24,084,480 (mult of 15)

    const int block = 256;
    const int grid  = 2048;   // 8192 waves = exactly max residency (32 waves/CU)
    yolo_loss_kernel<<<grid, block, 0, stream>>>(pre, gt, out, total_f4);
}

// Round 4
// 143.209 us; speedup vs baseline: 1.0089x; 1.0089x over previous
//
#include <hip/hip_runtime.h>

// YOLO loss: per-cell masked squared-error reduction over [B,7,7,30] fp32 x2.
// Per cell: mask = (gt[...,4] == 1.0)
//   per_cell = mask ? 5*sum((pre[0:4]-gt[0:4])^2) + 10*(pre[4]-gt[4])^2
//                   : 0.5*(pre[4]-gt[4])^2
// Output: scalar sum, shape (1,).
//
// Layout: 2-cell period = 60 floats = 240 B. Needed channels (0..4 per cell)
// live in two 32 B-contiguous, 16 B-aligned spans per period:
//   cell0: bytes [q*240 +  0, +32)  -> coords A.xyzw, conf B.x
//   cell1: bytes [q*240 +112, +144) -> coords {A.z,A.w,B.x,B.y}, conf B.z
// One lane per cell, two aligned float4 loads per buffer. Mask is lane-local:
// NO shuffles, NO DS ops, NO divergent fixups -> clean unrollable loop.

__global__ __launch_bounds__(256) void yolo_loss_kernel(
    const float* __restrict__ pre,
    const float* __restrict__ gt,
    float* __restrict__ out,
    unsigned int n_cells)
{
    unsigned int tid    = blockIdx.x * blockDim.x + threadIdx.x;
    unsigned int stride = gridDim.x * blockDim.x;   // even -> (m&1) const/thread

    float acc = 0.0f;
    for (unsigned int m = tid; m < n_cells; m += stride) {
        unsigned int q    = m >> 1;
        bool         hi   = (m & 1u);
        size_t base = (size_t)q * 60 + (hi ? 28 : 0);   // float index; 16B-aligned

        const float4 pa = *reinterpret_cast<const float4*>(pre + base);
        const float4 pb = *reinterpret_cast<const float4*>(pre + base + 4);
        const float4 ga = *reinterpret_cast<const float4*>(gt  + base);
        const float4 gb = *reinterpret_cast<const float4*>(gt  + base + 4);

        float p0 = hi ? pa.z : pa.x;
        float p1 = hi ? pa.w : pa.y;
        float p2 = hi ? pb.x : pa.z;
        float p3 = hi ? pb.y : pa.w;
        float pc = hi ? pb.z : pb.x;
        float g0 = hi ? ga.z : ga.x;
        float g1 = hi ? ga.w : ga.y;
        float g2 = hi ? gb.x : ga.z;
        float g3 = hi ? gb.y : ga.w;
        float gc = hi ? gb.z : gb.x;

        float d0 = p0 - g0, d1 = p1 - g1, d2 = p2 - g2, d3 = p3 - g3;
        float dc = pc - gc;
        float coord = d0 * d0 + d1 * d1 + d2 * d2 + d3 * d3;
        float conf  = dc * dc;

        acc += (gc == 1.0f) ? fmaf(5.0f, coord, 10.0f * conf) : 0.5f * conf;
    }

    // wave-64 shuffle-down reduction
    for (int offr = 32; offr > 0; offr >>= 1)
        acc += __shfl_down(acc, offr, 64);

    __shared__ float s[4];
    int lane = threadIdx.x & 63;
    int wid  = threadIdx.x >> 6;
    if (lane == 0) s[wid] = acc;
    __syncthreads();

    if (threadIdx.x == 0) {
        float total = s[0] + s[1] + s[2] + s[3];
        atomicAdd(out, total);   // device-scope by default on CDNA
    }
}

extern "C" void kernel_launch(void* const* d_in, const int* in_sizes, int n_in,
                              void* d_out, int out_size, void* d_ws, size_t ws_size,
                              hipStream_t stream) {
    const float* pre = (const float*)d_in[0];
    const float* gt  = (const float*)d_in[1];
    float* out = (float*)d_out;

    // d_out is poisoned once and never re-poisoned between replays: zero it
    // ourselves every call (stream op — graph-capture safe).
    hipMemsetAsync(out, 0, sizeof(float), stream);

    unsigned int n_cells = (unsigned int)((long long)in_sizes[0] / 30);  // 3,211,264

    const int block = 256;
    const int grid  = 2048;   // 8192 waves; ~6.1 cells/thread
    yolo_loss_kernel<<<grid, block, 0, stream>>>(pre, gt, out, n_cells);
}